// Round 10
// baseline (196.523 us; speedup 1.0000x reference)
//
#include <hip/hip_runtime.h>

#define SPHN 9
#define CHN 64
#define TABLE_N 8193              // samples on [0,6], dt = 6/8192
#define TABLE_DT (6.0f / 8192.0f)
#define TABLE_INV_DT (8192.0f / 6.0f)

// ---------------------------------------------------------------------------
// Setup: parallel Wigner-J build (l=1 -> Jout[0..8], l=2 -> Jout[9..33]) in
// double precision (exact reference transcription), PLUS zeroing of counts[N].
// ---------------------------------------------------------------------------
__device__ __forceinline__ void centry(int l, int r, int c, double& re, double& im)
{
    const double is2 = 0.70710678118654752440;
    re = 0.0; im = 0.0;
    int m = r - l;
    if (m == 0) {
        if (c == l) re = 1.0;
    } else if (m > 0) {
        if (c == l - m) re = is2;
        else if (c == l + m) re = (m & 1) ? -is2 : is2;
    } else {
        if (c == l + m) im = is2;
        else if (c == l - m) im = (m & 1) ? is2 : -is2;
    }
}

__global__ __launch_bounds__(256) void k_setup(float* __restrict__ Jout,
                                               int* __restrict__ counts, int N)
{
    int gid = blockIdx.x * 256 + threadIdx.x;
    if (counts != nullptr && gid < N) counts[gid] = 0;
    if (blockIdx.x != 0) return;

    const int tid = threadIdx.x;
    __shared__ double factS[9];
    __shared__ double dS[34];
    if (tid < 9) {
        double f = 1.0;
        for (int q = 2; q <= tid; ++q) f *= (double)q;
        factS[tid] = f;
    }
    __syncthreads();

    int l = 0, i = 0, j = 0, base = 0, n = 0;
    bool active = false;
    if (tid < 9)       { l = 1; n = 3; base = 0; i = tid / 3;       j = tid % 3;       active = true; }
    else if (tid < 34) { l = 2; n = 5; base = 9; i = (tid - 9) / 5; j = (tid - 9) % 5; active = true; }

    if (active) {
        const double is2 = 0.70710678118654752440;
        int mp = i - l, m = j - l;
        double val = 0.0;
        int k0 = (m - mp) > 0 ? (m - mp) : 0;
        int k1 = (l + m < l - mp) ? (l + m) : (l - mp);
        for (int k = k0; k <= k1; ++k) {
            double sign = ((mp - m + k) & 1) ? -1.0 : 1.0;
            double num = sign * sqrt(factS[l + mp] * factS[l - mp] * factS[l + m] * factS[l - m]);
            double den = factS[l + m - k] * factS[k] * factS[mp - m + k] * factS[l - mp - k];
            double cp = 1.0;
            for (int q = 0; q < 2 * l + m - mp - 2 * k; ++q) cp *= is2;
            double sp = 1.0;
            for (int q = 0; q < mp - m + 2 * k; ++q) sp *= is2;
            val += num / den * cp * sp;
        }
        dS[base + i * n + j] = val;
    }
    __syncthreads();

    if (active) {
        const int n1 = n - 1;
        double jr = 0.0;
        double cjr, cji, ckr, cki;
        {
            int k = i;
            centry(l, j, j, cjr, cji);
            double tr = dS[base + k * n + j] * cjr;
            double ti = -dS[base + k * n + j] * cji;
            if (n1 - j != j) {
                centry(l, j, n1 - j, cjr, cji);
                tr += dS[base + k * n + (n1 - j)] * cjr;
                ti += -dS[base + k * n + (n1 - j)] * cji;
            }
            centry(l, i, i, ckr, cki);
            jr += ckr * tr - cki * ti;
        }
        if (n1 - i != i) {
            int k = n1 - i;
            centry(l, j, j, cjr, cji);
            double tr = dS[base + k * n + j] * cjr;
            double ti = -dS[base + k * n + j] * cji;
            if (n1 - j != j) {
                centry(l, j, n1 - j, cjr, cji);
                tr += dS[base + k * n + (n1 - j)] * cjr;
                ti += -dS[base + k * n + (n1 - j)] * cji;
            }
            centry(l, i, n1 - i, ckr, cki);
            jr += ckr * tr - cki * ti;
        }
        Jout[base + i * n + j] = (float)jr;
    }
}

__device__ __forceinline__ float siluf(float x) { return x / (1.f + expf(-x)); }

// ---------------------------------------------------------------------------
// Fused xm + radtab kernel (disjoint block ranges).
//  blocks [0, XB):    xm = node_feats @ W_msg1, rows {1,3,4,5,7,8},
//                     NEW layout xm6[node][64][8] (float4+float2 per lane)
//  blocks [XB, XB+RB): radial table T[s][c], 64 samples/block
// ---------------------------------------------------------------------------
__global__ __launch_bounds__(256) void k_xmrad(const float* __restrict__ nf,
                                               const float* __restrict__ m1,
                                               float* __restrict__ xm6, int N, int XB,
                                               const float* __restrict__ w1,
                                               const float* __restrict__ b1,
                                               const float* __restrict__ w2,
                                               float* __restrict__ table)
{
    __shared__ float rbfT[64 * 64];   // radtab: [k][s]; xm: aliased as sx[4][384]
    __shared__ float hT[128 * 64];
    __shared__ float distS[64];
    __shared__ float envS[64];
    const int tid = threadIdx.x;

    if (blockIdx.x < XB) {
        // ---------------- xm part ----------------
        float* sx = rbfT;             // 4*384 = 1536 floats <= 4096
        const int w = tid >> 6;
        const int t = tid & 63;
        const int n = blockIdx.x * 4 + w;
        if (n < N) {
            const float* xp = nf + (size_t)n * (SPHN * CHN);
            sx[w * 384 + 0 * 64 + t] = xp[1 * 64 + t];
            sx[w * 384 + 1 * 64 + t] = xp[3 * 64 + t];
            sx[w * 384 + 2 * 64 + t] = xp[4 * 64 + t];
            sx[w * 384 + 3 * 64 + t] = xp[5 * 64 + t];
            sx[w * 384 + 4 * 64 + t] = xp[7 * 64 + t];
            sx[w * 384 + 5 * 64 + t] = xp[8 * 64 + t];
        }
        __syncthreads();
        if (n >= N) return;
        float a0 = 0.f, a1 = 0.f, a2 = 0.f, a3 = 0.f, a4 = 0.f, a5 = 0.f;
        for (int c = 0; c < 64; ++c) {
            float m = m1[c * 64 + t];
            a0 += sx[w * 384 + 0 * 64 + c] * m;
            a1 += sx[w * 384 + 1 * 64 + c] * m;
            a2 += sx[w * 384 + 2 * 64 + c] * m;
            a3 += sx[w * 384 + 3 * 64 + c] * m;
            a4 += sx[w * 384 + 4 * 64 + c] * m;
            a5 += sx[w * 384 + 5 * 64 + c] * m;
        }
        float* op = xm6 + (size_t)n * 512 + t * 8;
        float4 v4; v4.x = a0; v4.y = a1; v4.z = a2; v4.w = a3;
        float2 v2; v2.x = a4; v2.y = a5;
        *(float4*)&op[0] = v4;
        *(float2*)&op[4] = v2;
        return;
    }

    // ---------------- radtab part ----------------
    const int base = (blockIdx.x - XB) * 64;
    if (tid < 64) {
        float dist = (float)(base + tid) * TABLE_DT;
        distS[tid] = dist;
        float dd = dist * (1.0f / 6.0f);
        float env = 0.f;
        if (dd < 1.0f) {
            float d2 = dd * dd;
            float d5 = d2 * d2 * dd;
            env = 1.0f - 21.0f * d5 + 35.0f * d5 * dd - 15.0f * d5 * d2;
        }
        envS[tid] = env;
    }
    __syncthreads();
    const float step = 6.0f / 63.0f;
#pragma unroll
    for (int p = 0; p < 16; ++p) {
        int idx = p * 256 + tid;
        int k = idx >> 6, s2 = idx & 63;
        float diff = distS[s2] - step * (float)k;
        rbfT[idx] = __expf(-55.125f * diff * diff);
    }
    __syncthreads();

    {
        const int sg = tid & 15;
        const int jg = tid >> 4;
        float hacc[4][8];
        float4 b0 = *(const float4*)&b1[jg * 8];
        float4 b4 = *(const float4*)&b1[jg * 8 + 4];
#pragma unroll
        for (int ee = 0; ee < 4; ++ee) {
            hacc[ee][0] = b0.x; hacc[ee][1] = b0.y; hacc[ee][2] = b0.z; hacc[ee][3] = b0.w;
            hacc[ee][4] = b4.x; hacc[ee][5] = b4.y; hacc[ee][6] = b4.z; hacc[ee][7] = b4.w;
        }
#pragma unroll 4
        for (int k = 0; k < 64; ++k) {
            float4 wa = *(const float4*)&w1[k * 128 + jg * 8];
            float4 wb = *(const float4*)&w1[k * 128 + jg * 8 + 4];
            float4 rb = *(const float4*)&rbfT[k * 64 + sg * 4];
            float r[4] = {rb.x, rb.y, rb.z, rb.w};
#pragma unroll
            for (int ee = 0; ee < 4; ++ee) {
                hacc[ee][0] += r[ee] * wa.x;
                hacc[ee][1] += r[ee] * wa.y;
                hacc[ee][2] += r[ee] * wa.z;
                hacc[ee][3] += r[ee] * wa.w;
                hacc[ee][4] += r[ee] * wb.x;
                hacc[ee][5] += r[ee] * wb.y;
                hacc[ee][6] += r[ee] * wb.z;
                hacc[ee][7] += r[ee] * wb.w;
            }
        }
#pragma unroll
        for (int jj = 0; jj < 8; ++jj) {
            float4 hv;
            hv.x = siluf(hacc[0][jj]);
            hv.y = siluf(hacc[1][jj]);
            hv.z = siluf(hacc[2][jj]);
            hv.w = siluf(hacc[3][jj]);
            *(float4*)&hT[(jg * 8 + jj) * 64 + sg * 4] = hv;
        }
    }
    __syncthreads();

    {
        const int sg = tid >> 4;
        const int tg = tid & 15;
        float acc[4][4];
#pragma unroll
        for (int ee = 0; ee < 4; ++ee)
#pragma unroll
            for (int tt = 0; tt < 4; ++tt) acc[ee][tt] = 0.f;
#pragma unroll 4
        for (int j = 0; j < 128; ++j) {
            float4 wv = *(const float4*)&w2[j * 64 + tg * 4];
            float4 hv = *(const float4*)&hT[j * 64 + sg * 4];
            float h[4] = {hv.x, hv.y, hv.z, hv.w};
#pragma unroll
            for (int ee = 0; ee < 4; ++ee) {
                acc[ee][0] += h[ee] * wv.x;
                acc[ee][1] += h[ee] * wv.y;
                acc[ee][2] += h[ee] * wv.z;
                acc[ee][3] += h[ee] * wv.w;
            }
        }
#pragma unroll
        for (int ee = 0; ee < 4; ++ee) {
            int s = base + sg * 4 + ee;
            if (s < TABLE_N) {
                float envv = envS[sg * 4 + ee];
                float4 o;
                o.x = acc[ee][0] * envv;
                o.y = acc[ee][1] * envv;
                o.z = acc[ee][2] * envv;
                o.w = acc[ee][3] * envv;
                *(float4*)&table[(size_t)s * 64 + tg * 4] = o;
            }
        }
    }
}

// ---------------------------------------------------------------------------
// Histogram of dst
// ---------------------------------------------------------------------------
__global__ __launch_bounds__(256) void k_hist(const int* __restrict__ eidx,
                                              int* __restrict__ counts, int E)
{
    int e = blockIdx.x * 256 + threadIdx.x;
    if (e < E) atomicAdd(&counts[eidx[E + e]], 1);
}

// ---------------------------------------------------------------------------
// Exclusive scan of counts[N] -> offsets/cursors, offsets[N]=total.
// ---------------------------------------------------------------------------
__global__ __launch_bounds__(1024) void k_scan(const int* __restrict__ counts,
                                               int* __restrict__ offsets,
                                               int* __restrict__ cursors, int N)
{
    __shared__ int wsum[16];
    __shared__ int wpre[16];
    const int tid = threadIdx.x;
    const int lane = tid & 63;
    const int wid = tid >> 6;
    const int per = (N + 1023) >> 10;
    const int begin = tid * per;
    const int endi = (begin + per < N) ? (begin + per) : N;

    int s = 0;
    for (int i = begin; i < endi; ++i) s += counts[i];

    int inc = s;
#pragma unroll
    for (int off = 1; off < 64; off <<= 1) {
        int u = __shfl_up(inc, off, 64);
        if (lane >= off) inc += u;
    }
    if (lane == 63) wsum[wid] = inc;
    __syncthreads();
    if (wid == 0) {
        int v = (lane < 16) ? wsum[lane] : 0;
        int winc = v;
#pragma unroll
        for (int off = 1; off < 16; off <<= 1) {
            int u = __shfl_up(winc, off, 64);
            if (lane >= off) winc += u;
        }
        if (lane < 16) wpre[lane] = winc - v;
    }
    __syncthreads();
    int run = wpre[wid] + (inc - s);
    for (int i = begin; i < endi; ++i) {
        int c = counts[i];
        offsets[i] = run;
        cursors[i] = run;
        run += c;
    }
    if (endi == N && begin < N) offsets[N] = run;
}

// ---------------------------------------------------------------------------
// Fused per-edge kernel: one thread per ORIGINAL edge e (coalesced evec read).
// Computes Wigner Q (20 live coeffs) + dist, claims sorted position pos via
// cursor atomic, writes Qe24[pos] (6 x float4: q0..q4, [dist,pad]) and
// srcs[pos]. Replaces k_scatter + k_edgeQ; perm array eliminated.
// ---------------------------------------------------------------------------
__global__ __launch_bounds__(256) void k_edgeQS(const float* __restrict__ evec,
                                                const int* __restrict__ eidx,
                                                const float* __restrict__ Jc,
                                                int* __restrict__ cursors,
                                                float* __restrict__ Qe24,
                                                int* __restrict__ srcs, int E)
{
    __shared__ float sJ[34];
    const int tid = threadIdx.x;
    if (tid < 34) sJ[tid] = Jc[tid];
    __syncthreads();

    const int e = blockIdx.x * 256 + tid;
    if (e >= E) return;

    float vx = evec[(size_t)e * 3 + 0];
    float vy = evec[(size_t)e * 3 + 1];
    float vz = evec[(size_t)e * 3 + 2];
    float dist = sqrtf(vx * vx + vy * vy + vz * vz);
    float inv = 1.0f / fmaxf(dist, 1e-7f);
    float xn = fminf(fmaxf(vx * inv, -1.f), 1.f);
    float yn = fminf(fmaxf(vy * inv, -1.f), 1.f);
    float zn = fminf(fmaxf(vz * inv, -1.f), 1.f);
    float beta = acosf(fminf(fmaxf(yn, -1.f + 1e-7f), 1.f - 1e-7f));
    float alpha = atan2f(xn, zn);
    const float bA = -beta;
    const float cA = -alpha;

    const int src = eidx[e];
    const int dst = eidx[E + e];
    const int pos = atomicAdd(&cursors[dst], 1);
    srcs[pos] = src;
    float* qo = Qe24 + (size_t)pos * 24;

    // ---- Wigner l = 1 ----
    {
        const float* J1 = sJ;
        float cb[3], sb[3], cz[3], sz[3];
#pragma unroll
        for (int k = 0; k < 3; ++k) {
            __sincosf((float)(1 - k) * bA, &sb[k], &cb[k]);
            __sincosf((float)(k - 1) * cA, &sz[k], &cz[k]);
        }
        cb[1] = 0.f; cz[1] = 0.f;
        float A[2][3], Bc[3][2], W[2][2];
#pragma unroll
        for (int a = 0; a < 2; ++a) {
            int r = a * 2;
#pragma unroll
            for (int m = 0; m < 3; ++m)
                A[a][m] = J1[r * 3 + m] * cb[m] + J1[r * 3 + (2 - m)] * sb[2 - m];
        }
#pragma unroll
        for (int m = 0; m < 3; ++m)
#pragma unroll
            for (int b = 0; b < 2; ++b) {
                int c = b * 2;
                Bc[m][b] = J1[m * 3 + c] * cz[c] + J1[m * 3 + (2 - c)] * sz[c];
            }
#pragma unroll
        for (int a = 0; a < 2; ++a)
#pragma unroll
            for (int b = 0; b < 2; ++b) {
                float w = 0.f;
#pragma unroll
                for (int m = 0; m < 3; ++m) w += A[a][m] * Bc[m][b];
                W[a][b] = w;
            }
        float4 q;
        q.x = W[0][0] * W[0][0] + W[1][0] * W[1][0];
        q.y = W[0][0] * W[0][1] + W[1][0] * W[1][1];
        q.z = W[0][1] * W[0][0] + W[1][1] * W[1][0];
        q.w = W[0][1] * W[0][1] + W[1][1] * W[1][1];
        *(float4*)&qo[0] = q;
    }

    // ---- Wigner l = 2 ----
    {
        const float* J2 = sJ + 9;
        float cb[5], sb[5], cz[5], sz[5];
#pragma unroll
        for (int k = 0; k < 5; ++k) {
            __sincosf((float)(2 - k) * bA, &sb[k], &cb[k]);
            __sincosf((float)(k - 2) * cA, &sz[k], &cz[k]);
        }
        cb[2] = 0.f; cz[2] = 0.f;
        const int rmap[4] = {0, 1, 3, 4};
        float A[4][5], Bc[5][4], W[4][4];
#pragma unroll
        for (int a = 0; a < 4; ++a) {
            int r = rmap[a];
#pragma unroll
            for (int m = 0; m < 5; ++m)
                A[a][m] = J2[r * 5 + m] * cb[m] + J2[r * 5 + (4 - m)] * sb[4 - m];
        }
#pragma unroll
        for (int m = 0; m < 5; ++m)
#pragma unroll
            for (int b = 0; b < 4; ++b) {
                int c = rmap[b];
                Bc[m][b] = J2[m * 5 + c] * cz[c] + J2[m * 5 + (4 - c)] * sz[c];
            }
#pragma unroll
        for (int a = 0; a < 4; ++a)
#pragma unroll
            for (int b = 0; b < 4; ++b) {
                float w = 0.f;
#pragma unroll
                for (int m = 0; m < 5; ++m) w += A[a][m] * Bc[m][b];
                W[a][b] = w;
            }
#pragma unroll
        for (int a = 0; a < 4; ++a) {
            float4 q;
            q.x = W[0][a] * W[0][0] + W[1][a] * W[1][0] + W[2][a] * W[2][0] + W[3][a] * W[3][0];
            q.y = W[0][a] * W[0][1] + W[1][a] * W[1][1] + W[2][a] * W[2][1] + W[3][a] * W[3][1];
            q.z = W[0][a] * W[0][2] + W[1][a] * W[1][2] + W[2][a] * W[2][2] + W[3][a] * W[3][2];
            q.w = W[0][a] * W[0][3] + W[1][a] * W[1][3] + W[2][a] * W[2][3] + W[3][a] * W[3][3];
            *(float4*)&qo[4 + a * 4] = q;
        }
    }

    float4 qd; qd.x = dist; qd.y = 0.f; qd.z = 0.f; qd.w = 0.f;
    *(float4*)&qo[20] = qd;
}

// ---------------------------------------------------------------------------
// Per-dst-node gather: Qe24/srcs sequential; rad via table interpolation;
// xm6[src] (float4+float2) is the only random stream. Fused M2/RMS/gamma.
// ---------------------------------------------------------------------------
__global__ __launch_bounds__(64) void k_gather_fin(const int* __restrict__ srcs,
                                                   const int* __restrict__ offsets,
                                                   const float* __restrict__ Qe24,
                                                   const float* __restrict__ table,
                                                   const float* __restrict__ xm6,
                                                   const float* __restrict__ m2,
                                                   const float* __restrict__ gam,
                                                   float* __restrict__ out)
{
    const int n = blockIdx.x;
    const int t = threadIdx.x;
    const int start = offsets[n];
    const int end = offsets[n + 1];

    float a1 = 0.f, a3 = 0.f, a4 = 0.f, a5 = 0.f, a7 = 0.f, a8 = 0.f;
    for (int i = start; i < end; ++i) {
        const int src = srcs[i];
        const float* q = Qe24 + (size_t)i * 24;
        float4 q0 = *(const float4*)&q[0];
        float4 q1 = *(const float4*)&q[4];
        float4 q2 = *(const float4*)&q[8];
        float4 q3 = *(const float4*)&q[12];
        float4 q4 = *(const float4*)&q[16];
        float dist = q[20];

        float u = fminf(dist * TABLE_INV_DT, 8192.0f);
        int iu = (int)u;
        iu = (iu > 8191) ? 8191 : iu;
        float fr = u - (float)iu;
        const float* t0 = table + (size_t)iu * 64;
        float r0 = t0[t];
        float r1 = t0[64 + t];
        const float rad = r0 + fr * (r1 - r0);

        const float* xs = xm6 + (size_t)src * 512 + t * 8;
        float4 xa = *(const float4*)&xs[0];
        float2 xb = *(const float2*)&xs[4];
        float x1 = xa.x, x3 = xa.y, x4 = xa.z, x5 = xa.w, x7 = xb.x, x8 = xb.y;

        a1 += rad * (q0.x * x1 + q0.y * x3);
        a3 += rad * (q0.z * x1 + q0.w * x3);
        a4 += rad * (q1.x * x4 + q1.y * x5 + q1.z * x7 + q1.w * x8);
        a5 += rad * (q2.x * x4 + q2.y * x5 + q2.z * x7 + q2.w * x8);
        a7 += rad * (q3.x * x4 + q3.y * x5 + q3.z * x7 + q3.w * x8);
        a8 += rad * (q4.x * x4 + q4.y * x5 + q4.z * x7 + q4.w * x8);
    }

    __shared__ float sa[6 * 64];
    sa[0 * 64 + t] = a1;
    sa[1 * 64 + t] = a3;
    sa[2 * 64 + t] = a4;
    sa[3 * 64 + t] = a5;
    sa[4 * 64 + t] = a7;
    sa[5 * 64 + t] = a8;
    __syncthreads();
    float v0 = 0.f, v1 = 0.f, v2 = 0.f, v3 = 0.f, v4 = 0.f, v5 = 0.f;
    for (int c = 0; c < 64; ++c) {
        float m = m2[c * 64 + t];
        v0 += sa[0 * 64 + c] * m;
        v1 += sa[1 * 64 + c] * m;
        v2 += sa[2 * 64 + c] * m;
        v3 += sa[3 * 64 + c] * m;
        v4 += sa[4 * 64 + c] * m;
        v5 += sa[5 * 64 + c] * m;
    }
    float ss = v0 * v0 + v1 * v1 + v2 * v2 + v3 * v3 + v4 * v4 + v5 * v5;
    float rms = sqrtf(ss * (1.0f / 9.0f) + 1e-7f);
    float sc = gam[t] / rms;
    float* op = out + (size_t)n * 576;
    op[0 * 64 + t] = 0.f;
    op[2 * 64 + t] = 0.f;
    op[6 * 64 + t] = 0.f;
    op[1 * 64 + t] = v0 * sc;
    op[3 * 64 + t] = v1 * sc;
    op[4 * 64 + t] = v2 * sc;
    op[5 * 64 + t] = v3 * sc;
    op[7 * 64 + t] = v4 * sc;
    op[8 * 64 + t] = v5 * sc;
}

// ---------------------------------------------------------------------------
// Legacy fallback path (small ws): OLD-layout xm, LDS-phased rad, atomic
// scatter + separate finalize. Unchanged from round 6 path.
// ---------------------------------------------------------------------------
__global__ __launch_bounds__(256) void k_xm_legacy(const float* __restrict__ nf,
                                                   const float* __restrict__ m1,
                                                   float* __restrict__ xm6, int N)
{
    const int tid = threadIdx.x;
    const int w = tid >> 6;
    const int t = tid & 63;
    const int n = blockIdx.x * 4 + w;
    __shared__ float sx[4][6 * 64];
    if (n < N) {
        const float* xp = nf + (size_t)n * (SPHN * CHN);
        sx[w][0 * 64 + t] = xp[1 * 64 + t];
        sx[w][1 * 64 + t] = xp[3 * 64 + t];
        sx[w][2 * 64 + t] = xp[4 * 64 + t];
        sx[w][3 * 64 + t] = xp[5 * 64 + t];
        sx[w][4 * 64 + t] = xp[7 * 64 + t];
        sx[w][5 * 64 + t] = xp[8 * 64 + t];
    }
    __syncthreads();
    if (n >= N) return;
    float a0 = 0.f, a1 = 0.f, a2 = 0.f, a3 = 0.f, a4 = 0.f, a5 = 0.f;
    for (int c = 0; c < 64; ++c) {
        float m = m1[c * 64 + t];
        a0 += sx[w][0 * 64 + c] * m;
        a1 += sx[w][1 * 64 + c] * m;
        a2 += sx[w][2 * 64 + c] * m;
        a3 += sx[w][3 * 64 + c] * m;
        a4 += sx[w][4 * 64 + c] * m;
        a5 += sx[w][5 * 64 + c] * m;
    }
    float* op = xm6 + (size_t)n * 384;
    op[0 * 64 + t] = a0;
    op[1 * 64 + t] = a1;
    op[2 * 64 + t] = a2;
    op[3 * 64 + t] = a3;
    op[4 * 64 + t] = a4;
    op[5 * 64 + t] = a5;
}

__global__ __launch_bounds__(256, 4) void k_rad_lds(const float* __restrict__ evec,
                                                    const float* __restrict__ w1,
                                                    const float* __restrict__ b1,
                                                    const float* __restrict__ w2,
                                                    float* __restrict__ radg,
                                                    int E)
{
    __shared__ float rbfT[64 * 64];
    __shared__ float hT[32 * 64];
    __shared__ float distS[64];
    __shared__ float envS[64];
    const int tid = threadIdx.x;
    const int base = blockIdx.x * 64;

    if (tid < 64) {
        int e = base + tid;
        float dist = 0.f;
        if (e < E) {
            float vx = evec[(size_t)e * 3 + 0];
            float vy = evec[(size_t)e * 3 + 1];
            float vz = evec[(size_t)e * 3 + 2];
            dist = sqrtf(vx * vx + vy * vy + vz * vz);
        }
        distS[tid] = dist;
        float dd = dist * (1.0f / 6.0f);
        float env = 0.f;
        if (dd < 1.0f) {
            float d2 = dd * dd;
            float d5 = d2 * d2 * dd;
            env = 1.0f - 21.0f * d5 + 35.0f * d5 * dd - 15.0f * d5 * d2;
        }
        envS[tid] = env;
    }
    __syncthreads();

    const float step = 6.0f / 63.0f;
#pragma unroll
    for (int p = 0; p < 16; ++p) {
        int idx = p * 256 + tid;
        int k = idx >> 6, e2 = idx & 63;
        float diff = distS[e2] - step * (float)k;
        rbfT[idx] = __expf(-55.125f * diff * diff);
    }

    const int egB = tid & 15;
    const int jgB = tid >> 4;
    const int egC = tid >> 4;
    const int tgC = tid & 15;

    float acc[4][4];
#pragma unroll
    for (int ee = 0; ee < 4; ++ee)
#pragma unroll
        for (int cc = 0; cc < 4; ++cc) acc[ee][cc] = 0.f;

    for (int q = 0; q < 4; ++q) {
        float h00, h01, h10, h11, h20, h21, h30, h31;
        {
            const float2 bb = *(const float2*)&b1[q * 32 + jgB * 2];
            h00 = bb.x; h01 = bb.y; h10 = bb.x; h11 = bb.y;
            h20 = bb.x; h21 = bb.y; h30 = bb.x; h31 = bb.y;
            const float* w1p = w1 + q * 32 + jgB * 2;
#pragma unroll 4
            for (int k = 0; k < 64; ++k) {
                float2 wv = *(const float2*)&w1p[k * 128];
                float4 rb = *(const float4*)&rbfT[k * 64 + egB * 4];
                h00 += rb.x * wv.x; h01 += rb.x * wv.y;
                h10 += rb.y * wv.x; h11 += rb.y * wv.y;
                h20 += rb.z * wv.x; h21 += rb.z * wv.y;
                h30 += rb.w * wv.x; h31 += rb.w * wv.y;
            }
        }
        __syncthreads();
        {
            float4 v0, v1;
            v0.x = siluf(h00); v0.y = siluf(h10); v0.z = siluf(h20); v0.w = siluf(h30);
            v1.x = siluf(h01); v1.y = siluf(h11); v1.z = siluf(h21); v1.w = siluf(h31);
            *(float4*)&hT[(jgB * 2 + 0) * 64 + egB * 4] = v0;
            *(float4*)&hT[(jgB * 2 + 1) * 64 + egB * 4] = v1;
        }
        __syncthreads();

        const float* w2p = w2 + (size_t)(q * 32) * 64 + tgC * 4;
#pragma unroll 4
        for (int j2 = 0; j2 < 32; ++j2) {
            float4 wv = *(const float4*)&w2p[j2 * 64];
            float4 hv = *(const float4*)&hT[j2 * 64 + egC * 4];
            acc[0][0] += hv.x * wv.x; acc[0][1] += hv.x * wv.y;
            acc[0][2] += hv.x * wv.z; acc[0][3] += hv.x * wv.w;
            acc[1][0] += hv.y * wv.x; acc[1][1] += hv.y * wv.y;
            acc[1][2] += hv.y * wv.z; acc[1][3] += hv.y * wv.w;
            acc[2][0] += hv.z * wv.x; acc[2][1] += hv.z * wv.y;
            acc[2][2] += hv.z * wv.z; acc[2][3] += hv.z * wv.w;
            acc[3][0] += hv.w * wv.x; acc[3][1] += hv.w * wv.y;
            acc[3][2] += hv.w * wv.z; acc[3][3] += hv.w * wv.w;
        }
    }

#pragma unroll
    for (int ee = 0; ee < 4; ++ee) {
        int e = base + egC * 4 + ee;
        if (e < E) {
            float envv = envS[egC * 4 + ee];
            float4 o;
            o.x = acc[ee][0] * envv;
            o.y = acc[ee][1] * envv;
            o.z = acc[ee][2] * envv;
            o.w = acc[ee][3] * envv;
            *(float4*)&radg[(size_t)e * 64 + tgC * 4] = o;
        }
    }
}

__device__ __forceinline__ float wig_entry(int l, int i, int j, float bA, float cA,
                                           const float* __restrict__ J, int n)
{
    if (i == l) return 0.f;
    const int j2 = 2 * l - j;
    float Pij = 0.f, Pij2 = 0.f;
    for (int k = 0; k < n; ++k) {
        float sbk, cbk;
        __sincosf((float)(l - k) * bA, &sbk, &cbk);
        if (k == l) cbk = 0.f;
        float zj  = cbk * J[k * n + j]  + sbk * J[(2 * l - k) * n + j];
        float zj2 = cbk * J[k * n + j2] + sbk * J[(2 * l - k) * n + j2];
        Pij  += J[i * n + k] * zj;
        Pij2 += J[i * n + k] * zj2;
    }
    float s_, c_;
    __sincosf((float)(l - j) * cA, &s_, &c_);
    float czj = (j == l) ? 0.f : c_;
    float szj = -s_;
    return Pij * czj + Pij2 * szj;
}

__global__ __launch_bounds__(64) void k_edge2(const float* __restrict__ evec,
                                              const int* __restrict__ eidx,
                                              const float* __restrict__ radg,
                                              const float* __restrict__ Jc,
                                              const float* __restrict__ xm6,
                                              float* __restrict__ acc, int E)
{
    const int e = blockIdx.x;
    const int t = threadIdx.x;
    __shared__ float s_W1[9], s_W2[25], s_Q1[9], s_Q2[25];

    float vx = evec[(size_t)e * 3 + 0];
    float vy = evec[(size_t)e * 3 + 1];
    float vz = evec[(size_t)e * 3 + 2];
    float dist = sqrtf(vx * vx + vy * vy + vz * vz);
    float inv = 1.0f / fmaxf(dist, 1e-7f);
    float xn = fminf(fmaxf(vx * inv, -1.f), 1.f);
    float yn = fminf(fmaxf(vy * inv, -1.f), 1.f);
    float zn = fminf(fmaxf(vz * inv, -1.f), 1.f);
    float beta = acosf(fminf(fmaxf(yn, -1.f + 1e-7f), 1.f - 1e-7f));
    float alpha = atan2f(xn, zn);
    float bA = -beta;
    float cA = -alpha;

    if (t < 25) {
        s_W2[t] = wig_entry(2, t / 5, t % 5, bA, cA, Jc + 9, 5);
    } else if (t >= 32 && t < 41) {
        int u = t - 32;
        s_W1[u] = wig_entry(1, u / 3, u % 3, bA, cA, Jc, 3);
    }
    __syncthreads();

    if (t < 25) {
        int i = t / 5, j = t % 5;
        float qv = 0.f;
#pragma unroll
        for (int k = 0; k < 5; ++k) qv += s_W2[k * 5 + i] * s_W2[k * 5 + j];
        s_Q2[t] = qv;
    } else if (t >= 32 && t < 41) {
        int u = t - 32;
        int i = u / 3, j = u % 3;
        float qv = 0.f;
#pragma unroll
        for (int k = 0; k < 3; ++k) qv += s_W1[k * 3 + i] * s_W1[k * 3 + j];
        s_Q1[u] = qv;
    }
    __syncthreads();

    const float rad = radg[(size_t)e * 64 + t];
    const int src = eidx[e];
    const int dst = eidx[E + e];
    const float* xs = xm6 + (size_t)src * 384;
    float x1 = xs[0 * 64 + t];
    float x3 = xs[1 * 64 + t];
    float x4 = xs[2 * 64 + t];
    float x5 = xs[3 * 64 + t];
    float x7 = xs[4 * 64 + t];
    float x8 = xs[5 * 64 + t];

    float m1v = rad * (s_Q1[0] * x1 + s_Q1[2] * x3);
    float m3v = rad * (s_Q1[6] * x1 + s_Q1[8] * x3);
    float m4v = rad * (s_Q2[0]  * x4 + s_Q2[1]  * x5 + s_Q2[3]  * x7 + s_Q2[4]  * x8);
    float m5v = rad * (s_Q2[5]  * x4 + s_Q2[6]  * x5 + s_Q2[8]  * x7 + s_Q2[9]  * x8);
    float m7v = rad * (s_Q2[15] * x4 + s_Q2[16] * x5 + s_Q2[18] * x7 + s_Q2[19] * x8);
    float m8v = rad * (s_Q2[20] * x4 + s_Q2[21] * x5 + s_Q2[23] * x7 + s_Q2[24] * x8);

    float* ad = acc + (size_t)dst * 576;
    atomicAdd(ad + 1 * 64 + t, m1v);
    atomicAdd(ad + 3 * 64 + t, m3v);
    atomicAdd(ad + 4 * 64 + t, m4v);
    atomicAdd(ad + 5 * 64 + t, m5v);
    atomicAdd(ad + 7 * 64 + t, m7v);
    atomicAdd(ad + 8 * 64 + t, m8v);
}

__global__ __launch_bounds__(64) void k_fin(const float* __restrict__ m2,
                                            const float* __restrict__ gam,
                                            float* __restrict__ out)
{
    const int n = blockIdx.x;
    const int t = threadIdx.x;
    __shared__ float sa[6 * 64];
    float* op = out + (size_t)n * 576;
    sa[0 * 64 + t] = op[1 * 64 + t];
    sa[1 * 64 + t] = op[3 * 64 + t];
    sa[2 * 64 + t] = op[4 * 64 + t];
    sa[3 * 64 + t] = op[5 * 64 + t];
    sa[4 * 64 + t] = op[7 * 64 + t];
    sa[5 * 64 + t] = op[8 * 64 + t];
    __syncthreads();
    float v0 = 0.f, v1 = 0.f, v2 = 0.f, v3 = 0.f, v4 = 0.f, v5 = 0.f;
    for (int c = 0; c < 64; ++c) {
        float m = m2[c * 64 + t];
        v0 += sa[0 * 64 + c] * m;
        v1 += sa[1 * 64 + c] * m;
        v2 += sa[2 * 64 + c] * m;
        v3 += sa[3 * 64 + c] * m;
        v4 += sa[4 * 64 + c] * m;
        v5 += sa[5 * 64 + c] * m;
    }
    float ss = v0 * v0 + v1 * v1 + v2 * v2 + v3 * v3 + v4 * v4 + v5 * v5;
    float rms = sqrtf(ss * (1.0f / 9.0f) + 1e-7f);
    float sc = gam[t] / rms;
    op[0 * 64 + t] = 0.f;
    op[2 * 64 + t] = 0.f;
    op[6 * 64 + t] = 0.f;
    op[1 * 64 + t] = v0 * sc;
    op[3 * 64 + t] = v1 * sc;
    op[4 * 64 + t] = v2 * sc;
    op[5 * 64 + t] = v3 * sc;
    op[7 * 64 + t] = v4 * sc;
    op[8 * 64 + t] = v5 * sc;
}

static inline size_t align256(size_t x) { return (x + 255) & ~(size_t)255; }

extern "C" void kernel_launch(void* const* d_in, const int* in_sizes, int n_in,
                              void* d_out, int out_size, void* d_ws, size_t ws_size,
                              hipStream_t stream)
{
    const float* nf  = (const float*)d_in[0];
    const float* ev  = (const float*)d_in[1];
    const int*   ei  = (const int*)d_in[2];
    const float* w1  = (const float*)d_in[3];
    const float* b1  = (const float*)d_in[4];
    const float* w2  = (const float*)d_in[5];
    const float* m1  = (const float*)d_in[6];
    const float* m2  = (const float*)d_in[7];
    const float* gam = (const float*)d_in[8];

    const int N = in_sizes[0] / (SPHN * CHN);
    const int E = in_sizes[1] / 3;

    float* out = (float*)d_out;
    char* base = (char*)d_ws;

    // ---- New-path layout ----
    size_t off = 0;
    float* Jc = (float*)(base + off);      off += align256(34 * sizeof(float));
    float* xm6n = (float*)(base + off);    off += align256((size_t)N * 512 * sizeof(float));
    float* table = (float*)(base + off);   off += align256((size_t)TABLE_N * 64 * sizeof(float));
    float* Qe24 = (float*)(base + off);    off += align256((size_t)E * 24 * sizeof(float));
    int* counts = (int*)(base + off);      off += align256((size_t)N * sizeof(int));
    int* offsets = (int*)(base + off);     off += align256((size_t)(N + 1) * sizeof(int));
    int* cursors = (int*)(base + off);     off += align256((size_t)N * sizeof(int));
    int* srcs = (int*)(base + off);        off += align256((size_t)E * sizeof(int));
    size_t need_new = off;

    // ---- Fallback layout (shares Jc at 0) ----
    size_t offF = align256(34 * sizeof(float));
    float* xm6o = (float*)(base + offF);   offF += align256((size_t)N * 384 * sizeof(float));
    float* radg = (float*)(base + offF);   offF += align256((size_t)E * 64 * sizeof(float));
    size_t need_old = offF;

    if (ws_size >= need_new) {
        const int XB = (N + 3) / 4;
        const int RB = (TABLE_N + 63) / 64;
        hipLaunchKernelGGL(k_setup, dim3((N + 255) / 256), dim3(256), 0, stream,
                           Jc, counts, N);
        hipLaunchKernelGGL(k_hist, dim3((E + 255) / 256), dim3(256), 0, stream,
                           ei, counts, E);
        hipLaunchKernelGGL(k_scan, dim3(1), dim3(1024), 0, stream,
                           counts, offsets, cursors, N);
        hipLaunchKernelGGL(k_xmrad, dim3(XB + RB), dim3(256), 0, stream,
                           nf, m1, xm6n, N, XB, w1, b1, w2, table);
        hipLaunchKernelGGL(k_edgeQS, dim3((E + 255) / 256), dim3(256), 0, stream,
                           ev, ei, Jc, cursors, Qe24, srcs, E);
        hipLaunchKernelGGL(k_gather_fin, dim3(N), dim3(64), 0, stream,
                           srcs, offsets, Qe24, table, xm6n, m2, gam, out);
    } else if (ws_size >= need_old) {
        hipLaunchKernelGGL(k_setup, dim3(1), dim3(256), 0, stream,
                           Jc, (int*)nullptr, 0);
        hipLaunchKernelGGL(k_xm_legacy, dim3((N + 3) / 4), dim3(256), 0, stream,
                           nf, m1, xm6o, N);
        hipMemsetAsync(d_out, 0, (size_t)out_size * sizeof(float), stream);
        hipLaunchKernelGGL(k_rad_lds, dim3((E + 63) / 64), dim3(256), 0, stream,
                           ev, w1, b1, w2, radg, E);
        hipLaunchKernelGGL(k_edge2, dim3(E), dim3(64), 0, stream,
                           ev, ei, radg, Jc, xm6o, out, E);
        hipLaunchKernelGGL(k_fin, dim3(N), dim3(64), 0, stream, m2, gam, out);
    }
}

// Round 11
// 193.916 us; speedup vs baseline: 1.0134x; 1.0134x over previous
//
#include <hip/hip_runtime.h>

#define SPHN 9
#define CHN 64
#define TABLE_N 8193              // samples on [0,6], dt = 6/8192
#define TABLE_DT (6.0f / 8192.0f)
#define TABLE_INV_DT (8192.0f / 6.0f)

// ---------------------------------------------------------------------------
// Setup: parallel Wigner-J build (l=1 -> Jout[0..8], l=2 -> Jout[9..33]) in
// double precision (exact reference transcription), PLUS zeroing of counts[N].
// ---------------------------------------------------------------------------
__device__ __forceinline__ void centry(int l, int r, int c, double& re, double& im)
{
    const double is2 = 0.70710678118654752440;
    re = 0.0; im = 0.0;
    int m = r - l;
    if (m == 0) {
        if (c == l) re = 1.0;
    } else if (m > 0) {
        if (c == l - m) re = is2;
        else if (c == l + m) re = (m & 1) ? -is2 : is2;
    } else {
        if (c == l + m) im = is2;
        else if (c == l - m) im = (m & 1) ? is2 : -is2;
    }
}

__global__ __launch_bounds__(256) void k_setup(float* __restrict__ Jout,
                                               int* __restrict__ counts, int N)
{
    int gid = blockIdx.x * 256 + threadIdx.x;
    if (counts != nullptr && gid < N) counts[gid] = 0;
    if (blockIdx.x != 0) return;

    const int tid = threadIdx.x;
    __shared__ double factS[9];
    __shared__ double dS[34];
    if (tid < 9) {
        double f = 1.0;
        for (int q = 2; q <= tid; ++q) f *= (double)q;
        factS[tid] = f;
    }
    __syncthreads();

    int l = 0, i = 0, j = 0, base = 0, n = 0;
    bool active = false;
    if (tid < 9)       { l = 1; n = 3; base = 0; i = tid / 3;       j = tid % 3;       active = true; }
    else if (tid < 34) { l = 2; n = 5; base = 9; i = (tid - 9) / 5; j = (tid - 9) % 5; active = true; }

    if (active) {
        const double is2 = 0.70710678118654752440;
        int mp = i - l, m = j - l;
        double val = 0.0;
        int k0 = (m - mp) > 0 ? (m - mp) : 0;
        int k1 = (l + m < l - mp) ? (l + m) : (l - mp);
        for (int k = k0; k <= k1; ++k) {
            double sign = ((mp - m + k) & 1) ? -1.0 : 1.0;
            double num = sign * sqrt(factS[l + mp] * factS[l - mp] * factS[l + m] * factS[l - m]);
            double den = factS[l + m - k] * factS[k] * factS[mp - m + k] * factS[l - mp - k];
            double cp = 1.0;
            for (int q = 0; q < 2 * l + m - mp - 2 * k; ++q) cp *= is2;
            double sp = 1.0;
            for (int q = 0; q < mp - m + 2 * k; ++q) sp *= is2;
            val += num / den * cp * sp;
        }
        dS[base + i * n + j] = val;
    }
    __syncthreads();

    if (active) {
        const int n1 = n - 1;
        double jr = 0.0;
        double cjr, cji, ckr, cki;
        {
            int k = i;
            centry(l, j, j, cjr, cji);
            double tr = dS[base + k * n + j] * cjr;
            double ti = -dS[base + k * n + j] * cji;
            if (n1 - j != j) {
                centry(l, j, n1 - j, cjr, cji);
                tr += dS[base + k * n + (n1 - j)] * cjr;
                ti += -dS[base + k * n + (n1 - j)] * cji;
            }
            centry(l, i, i, ckr, cki);
            jr += ckr * tr - cki * ti;
        }
        if (n1 - i != i) {
            int k = n1 - i;
            centry(l, j, j, cjr, cji);
            double tr = dS[base + k * n + j] * cjr;
            double ti = -dS[base + k * n + j] * cji;
            if (n1 - j != j) {
                centry(l, j, n1 - j, cjr, cji);
                tr += dS[base + k * n + (n1 - j)] * cjr;
                ti += -dS[base + k * n + (n1 - j)] * cji;
            }
            centry(l, i, n1 - i, ckr, cki);
            jr += ckr * tr - cki * ti;
        }
        Jout[base + i * n + j] = (float)jr;
    }
}

__device__ __forceinline__ float siluf(float x) { return x / (1.f + expf(-x)); }

// ---------------------------------------------------------------------------
// Per-node (4 nodes/block): xm = node_feats @ W_msg1, rows {1,3,4,5,7,8},
// output layout xm6[node][64][8] (float4+float2 per lane). LDS 6 KB.
// ---------------------------------------------------------------------------
__global__ __launch_bounds__(256) void k_xm(const float* __restrict__ nf,
                                            const float* __restrict__ m1,
                                            float* __restrict__ xm6, int N)
{
    const int tid = threadIdx.x;
    const int w = tid >> 6;
    const int t = tid & 63;
    const int n = blockIdx.x * 4 + w;
    __shared__ float sx[4][6 * 64];
    if (n < N) {
        const float* xp = nf + (size_t)n * (SPHN * CHN);
        sx[w][0 * 64 + t] = xp[1 * 64 + t];
        sx[w][1 * 64 + t] = xp[3 * 64 + t];
        sx[w][2 * 64 + t] = xp[4 * 64 + t];
        sx[w][3 * 64 + t] = xp[5 * 64 + t];
        sx[w][4 * 64 + t] = xp[7 * 64 + t];
        sx[w][5 * 64 + t] = xp[8 * 64 + t];
    }
    __syncthreads();
    if (n >= N) return;
    float a0 = 0.f, a1 = 0.f, a2 = 0.f, a3 = 0.f, a4 = 0.f, a5 = 0.f;
    for (int c = 0; c < 64; ++c) {
        float m = m1[c * 64 + t];
        a0 += sx[w][0 * 64 + c] * m;
        a1 += sx[w][1 * 64 + c] * m;
        a2 += sx[w][2 * 64 + c] * m;
        a3 += sx[w][3 * 64 + c] * m;
        a4 += sx[w][4 * 64 + c] * m;
        a5 += sx[w][5 * 64 + c] * m;
    }
    float* op = xm6 + (size_t)n * 512 + t * 8;
    float4 v4; v4.x = a0; v4.y = a1; v4.z = a2; v4.w = a3;
    float2 v2; v2.x = a4; v2.y = a5;
    *(float4*)&op[0] = v4;
    *(float2*)&op[4] = v2;
}

// ---------------------------------------------------------------------------
// Radial table build: T[s][c] = (silu(rbf(d_s)@W1+b1)@W2)[c] * env(d_s).
// 64 samples/block, 256 threads, LDS 48.5 KB (only 129 blocks — fine).
// ---------------------------------------------------------------------------
__global__ __launch_bounds__(256) void k_radtab(const float* __restrict__ w1,
                                                const float* __restrict__ b1,
                                                const float* __restrict__ w2,
                                                float* __restrict__ table)
{
    __shared__ float rbfT[64 * 64];   // [k][s]
    __shared__ float hT[128 * 64];    // [j][s]
    __shared__ float distS[64];
    __shared__ float envS[64];
    const int tid = threadIdx.x;
    const int base = blockIdx.x * 64;

    if (tid < 64) {
        float dist = (float)(base + tid) * TABLE_DT;
        distS[tid] = dist;
        float dd = dist * (1.0f / 6.0f);
        float env = 0.f;
        if (dd < 1.0f) {
            float d2 = dd * dd;
            float d5 = d2 * d2 * dd;
            env = 1.0f - 21.0f * d5 + 35.0f * d5 * dd - 15.0f * d5 * d2;
        }
        envS[tid] = env;
    }
    __syncthreads();
    const float step = 6.0f / 63.0f;
#pragma unroll
    for (int p = 0; p < 16; ++p) {
        int idx = p * 256 + tid;
        int k = idx >> 6, s2 = idx & 63;
        float diff = distS[s2] - step * (float)k;
        rbfT[idx] = __expf(-55.125f * diff * diff);
    }
    __syncthreads();

    {
        const int sg = tid & 15;
        const int jg = tid >> 4;
        float hacc[4][8];
        float4 b0 = *(const float4*)&b1[jg * 8];
        float4 b4 = *(const float4*)&b1[jg * 8 + 4];
#pragma unroll
        for (int ee = 0; ee < 4; ++ee) {
            hacc[ee][0] = b0.x; hacc[ee][1] = b0.y; hacc[ee][2] = b0.z; hacc[ee][3] = b0.w;
            hacc[ee][4] = b4.x; hacc[ee][5] = b4.y; hacc[ee][6] = b4.z; hacc[ee][7] = b4.w;
        }
#pragma unroll 4
        for (int k = 0; k < 64; ++k) {
            float4 wa = *(const float4*)&w1[k * 128 + jg * 8];
            float4 wb = *(const float4*)&w1[k * 128 + jg * 8 + 4];
            float4 rb = *(const float4*)&rbfT[k * 64 + sg * 4];
            float r[4] = {rb.x, rb.y, rb.z, rb.w};
#pragma unroll
            for (int ee = 0; ee < 4; ++ee) {
                hacc[ee][0] += r[ee] * wa.x;
                hacc[ee][1] += r[ee] * wa.y;
                hacc[ee][2] += r[ee] * wa.z;
                hacc[ee][3] += r[ee] * wa.w;
                hacc[ee][4] += r[ee] * wb.x;
                hacc[ee][5] += r[ee] * wb.y;
                hacc[ee][6] += r[ee] * wb.z;
                hacc[ee][7] += r[ee] * wb.w;
            }
        }
#pragma unroll
        for (int jj = 0; jj < 8; ++jj) {
            float4 hv;
            hv.x = siluf(hacc[0][jj]);
            hv.y = siluf(hacc[1][jj]);
            hv.z = siluf(hacc[2][jj]);
            hv.w = siluf(hacc[3][jj]);
            *(float4*)&hT[(jg * 8 + jj) * 64 + sg * 4] = hv;
        }
    }
    __syncthreads();

    {
        const int sg = tid >> 4;
        const int tg = tid & 15;
        float acc[4][4];
#pragma unroll
        for (int ee = 0; ee < 4; ++ee)
#pragma unroll
            for (int tt = 0; tt < 4; ++tt) acc[ee][tt] = 0.f;
#pragma unroll 4
        for (int j = 0; j < 128; ++j) {
            float4 wv = *(const float4*)&w2[j * 64 + tg * 4];
            float4 hv = *(const float4*)&hT[j * 64 + sg * 4];
            float h[4] = {hv.x, hv.y, hv.z, hv.w};
#pragma unroll
            for (int ee = 0; ee < 4; ++ee) {
                acc[ee][0] += h[ee] * wv.x;
                acc[ee][1] += h[ee] * wv.y;
                acc[ee][2] += h[ee] * wv.z;
                acc[ee][3] += h[ee] * wv.w;
            }
        }
#pragma unroll
        for (int ee = 0; ee < 4; ++ee) {
            int s = base + sg * 4 + ee;
            if (s < TABLE_N) {
                float envv = envS[sg * 4 + ee];
                float4 o;
                o.x = acc[ee][0] * envv;
                o.y = acc[ee][1] * envv;
                o.z = acc[ee][2] * envv;
                o.w = acc[ee][3] * envv;
                *(float4*)&table[(size_t)s * 64 + tg * 4] = o;
            }
        }
    }
}

// ---------------------------------------------------------------------------
// Histogram of dst
// ---------------------------------------------------------------------------
__global__ __launch_bounds__(256) void k_hist(const int* __restrict__ eidx,
                                              int* __restrict__ counts, int E)
{
    int e = blockIdx.x * 256 + threadIdx.x;
    if (e < E) atomicAdd(&counts[eidx[E + e]], 1);
}

// ---------------------------------------------------------------------------
// Exclusive scan of counts[N] -> offsets/cursors, offsets[N]=total.
// ---------------------------------------------------------------------------
__global__ __launch_bounds__(1024) void k_scan(const int* __restrict__ counts,
                                               int* __restrict__ offsets,
                                               int* __restrict__ cursors, int N)
{
    __shared__ int wsum[16];
    __shared__ int wpre[16];
    const int tid = threadIdx.x;
    const int lane = tid & 63;
    const int wid = tid >> 6;
    const int per = (N + 1023) >> 10;
    const int begin = tid * per;
    const int endi = (begin + per < N) ? (begin + per) : N;

    int s = 0;
    for (int i = begin; i < endi; ++i) s += counts[i];

    int inc = s;
#pragma unroll
    for (int off = 1; off < 64; off <<= 1) {
        int u = __shfl_up(inc, off, 64);
        if (lane >= off) inc += u;
    }
    if (lane == 63) wsum[wid] = inc;
    __syncthreads();
    if (wid == 0) {
        int v = (lane < 16) ? wsum[lane] : 0;
        int winc = v;
#pragma unroll
        for (int off = 1; off < 16; off <<= 1) {
            int u = __shfl_up(winc, off, 64);
            if (lane >= off) winc += u;
        }
        if (lane < 16) wpre[lane] = winc - v;
    }
    __syncthreads();
    int run = wpre[wid] + (inc - s);
    for (int i = begin; i < endi; ++i) {
        int c = counts[i];
        offsets[i] = run;
        cursors[i] = run;
        run += c;
    }
    if (endi == N && begin < N) offsets[N] = run;
}

// ---------------------------------------------------------------------------
// Fused per-edge kernel: one thread per ORIGINAL edge e (coalesced evec read).
// Computes Wigner Q (20 live coeffs) + dist, claims sorted position pos via
// cursor atomic, writes Qe24[pos] (6 x float4: q0..q4, [dist,pad]) and
// srcs[pos].
// ---------------------------------------------------------------------------
__global__ __launch_bounds__(256) void k_edgeQS(const float* __restrict__ evec,
                                                const int* __restrict__ eidx,
                                                const float* __restrict__ Jc,
                                                int* __restrict__ cursors,
                                                float* __restrict__ Qe24,
                                                int* __restrict__ srcs, int E)
{
    __shared__ float sJ[34];
    const int tid = threadIdx.x;
    if (tid < 34) sJ[tid] = Jc[tid];
    __syncthreads();

    const int e = blockIdx.x * 256 + tid;
    if (e >= E) return;

    float vx = evec[(size_t)e * 3 + 0];
    float vy = evec[(size_t)e * 3 + 1];
    float vz = evec[(size_t)e * 3 + 2];
    float dist = sqrtf(vx * vx + vy * vy + vz * vz);
    float inv = 1.0f / fmaxf(dist, 1e-7f);
    float xn = fminf(fmaxf(vx * inv, -1.f), 1.f);
    float yn = fminf(fmaxf(vy * inv, -1.f), 1.f);
    float zn = fminf(fmaxf(vz * inv, -1.f), 1.f);
    float beta = acosf(fminf(fmaxf(yn, -1.f + 1e-7f), 1.f - 1e-7f));
    float alpha = atan2f(xn, zn);
    const float bA = -beta;
    const float cA = -alpha;

    const int src = eidx[e];
    const int dst = eidx[E + e];
    const int pos = atomicAdd(&cursors[dst], 1);
    srcs[pos] = src;
    float* qo = Qe24 + (size_t)pos * 24;

    // ---- Wigner l = 1 ----
    {
        const float* J1 = sJ;
        float cb[3], sb[3], cz[3], sz[3];
#pragma unroll
        for (int k = 0; k < 3; ++k) {
            __sincosf((float)(1 - k) * bA, &sb[k], &cb[k]);
            __sincosf((float)(k - 1) * cA, &sz[k], &cz[k]);
        }
        cb[1] = 0.f; cz[1] = 0.f;
        float A[2][3], Bc[3][2], W[2][2];
#pragma unroll
        for (int a = 0; a < 2; ++a) {
            int r = a * 2;
#pragma unroll
            for (int m = 0; m < 3; ++m)
                A[a][m] = J1[r * 3 + m] * cb[m] + J1[r * 3 + (2 - m)] * sb[2 - m];
        }
#pragma unroll
        for (int m = 0; m < 3; ++m)
#pragma unroll
            for (int b = 0; b < 2; ++b) {
                int c = b * 2;
                Bc[m][b] = J1[m * 3 + c] * cz[c] + J1[m * 3 + (2 - c)] * sz[c];
            }
#pragma unroll
        for (int a = 0; a < 2; ++a)
#pragma unroll
            for (int b = 0; b < 2; ++b) {
                float w = 0.f;
#pragma unroll
                for (int m = 0; m < 3; ++m) w += A[a][m] * Bc[m][b];
                W[a][b] = w;
            }
        float4 q;
        q.x = W[0][0] * W[0][0] + W[1][0] * W[1][0];
        q.y = W[0][0] * W[0][1] + W[1][0] * W[1][1];
        q.z = W[0][1] * W[0][0] + W[1][1] * W[1][0];
        q.w = W[0][1] * W[0][1] + W[1][1] * W[1][1];
        *(float4*)&qo[0] = q;
    }

    // ---- Wigner l = 2 ----
    {
        const float* J2 = sJ + 9;
        float cb[5], sb[5], cz[5], sz[5];
#pragma unroll
        for (int k = 0; k < 5; ++k) {
            __sincosf((float)(2 - k) * bA, &sb[k], &cb[k]);
            __sincosf((float)(k - 2) * cA, &sz[k], &cz[k]);
        }
        cb[2] = 0.f; cz[2] = 0.f;
        const int rmap[4] = {0, 1, 3, 4};
        float A[4][5], Bc[5][4], W[4][4];
#pragma unroll
        for (int a = 0; a < 4; ++a) {
            int r = rmap[a];
#pragma unroll
            for (int m = 0; m < 5; ++m)
                A[a][m] = J2[r * 5 + m] * cb[m] + J2[r * 5 + (4 - m)] * sb[4 - m];
        }
#pragma unroll
        for (int m = 0; m < 5; ++m)
#pragma unroll
            for (int b = 0; b < 4; ++b) {
                int c = rmap[b];
                Bc[m][b] = J2[m * 5 + c] * cz[c] + J2[m * 5 + (4 - c)] * sz[c];
            }
#pragma unroll
        for (int a = 0; a < 4; ++a)
#pragma unroll
            for (int b = 0; b < 4; ++b) {
                float w = 0.f;
#pragma unroll
                for (int m = 0; m < 5; ++m) w += A[a][m] * Bc[m][b];
                W[a][b] = w;
            }
#pragma unroll
        for (int a = 0; a < 4; ++a) {
            float4 q;
            q.x = W[0][a] * W[0][0] + W[1][a] * W[1][0] + W[2][a] * W[2][0] + W[3][a] * W[3][0];
            q.y = W[0][a] * W[0][1] + W[1][a] * W[1][1] + W[2][a] * W[2][1] + W[3][a] * W[3][1];
            q.z = W[0][a] * W[0][2] + W[1][a] * W[1][2] + W[2][a] * W[2][2] + W[3][a] * W[3][2];
            q.w = W[0][a] * W[0][3] + W[1][a] * W[1][3] + W[2][a] * W[2][3] + W[3][a] * W[3][3];
            *(float4*)&qo[4 + a * 4] = q;
        }
    }

    float4 qd; qd.x = dist; qd.y = 0.f; qd.z = 0.f; qd.w = 0.f;
    *(float4*)&qo[20] = qd;
}

// ---------------------------------------------------------------------------
// Per-dst-node gather: Qe24/srcs sequential; rad via table interpolation;
// xm6[src] (float4+float2) is the only random stream. Fused M2/RMS/gamma.
// ---------------------------------------------------------------------------
__global__ __launch_bounds__(64) void k_gather_fin(const int* __restrict__ srcs,
                                                   const int* __restrict__ offsets,
                                                   const float* __restrict__ Qe24,
                                                   const float* __restrict__ table,
                                                   const float* __restrict__ xm6,
                                                   const float* __restrict__ m2,
                                                   const float* __restrict__ gam,
                                                   float* __restrict__ out)
{
    const int n = blockIdx.x;
    const int t = threadIdx.x;
    const int start = offsets[n];
    const int end = offsets[n + 1];

    float a1 = 0.f, a3 = 0.f, a4 = 0.f, a5 = 0.f, a7 = 0.f, a8 = 0.f;
    for (int i = start; i < end; ++i) {
        const int src = srcs[i];
        const float* q = Qe24 + (size_t)i * 24;
        float4 q0 = *(const float4*)&q[0];
        float4 q1 = *(const float4*)&q[4];
        float4 q2 = *(const float4*)&q[8];
        float4 q3 = *(const float4*)&q[12];
        float4 q4 = *(const float4*)&q[16];
        float dist = q[20];

        float u = fminf(dist * TABLE_INV_DT, 8192.0f);
        int iu = (int)u;
        iu = (iu > 8191) ? 8191 : iu;
        float fr = u - (float)iu;
        const float* t0 = table + (size_t)iu * 64;
        float r0 = t0[t];
        float r1 = t0[64 + t];
        const float rad = r0 + fr * (r1 - r0);

        const float* xs = xm6 + (size_t)src * 512 + t * 8;
        float4 xa = *(const float4*)&xs[0];
        float2 xb = *(const float2*)&xs[4];
        float x1 = xa.x, x3 = xa.y, x4 = xa.z, x5 = xa.w, x7 = xb.x, x8 = xb.y;

        a1 += rad * (q0.x * x1 + q0.y * x3);
        a3 += rad * (q0.z * x1 + q0.w * x3);
        a4 += rad * (q1.x * x4 + q1.y * x5 + q1.z * x7 + q1.w * x8);
        a5 += rad * (q2.x * x4 + q2.y * x5 + q2.z * x7 + q2.w * x8);
        a7 += rad * (q3.x * x4 + q3.y * x5 + q3.z * x7 + q3.w * x8);
        a8 += rad * (q4.x * x4 + q4.y * x5 + q4.z * x7 + q4.w * x8);
    }

    __shared__ float sa[6 * 64];
    sa[0 * 64 + t] = a1;
    sa[1 * 64 + t] = a3;
    sa[2 * 64 + t] = a4;
    sa[3 * 64 + t] = a5;
    sa[4 * 64 + t] = a7;
    sa[5 * 64 + t] = a8;
    __syncthreads();
    float v0 = 0.f, v1 = 0.f, v2 = 0.f, v3 = 0.f, v4 = 0.f, v5 = 0.f;
    for (int c = 0; c < 64; ++c) {
        float m = m2[c * 64 + t];
        v0 += sa[0 * 64 + c] * m;
        v1 += sa[1 * 64 + c] * m;
        v2 += sa[2 * 64 + c] * m;
        v3 += sa[3 * 64 + c] * m;
        v4 += sa[4 * 64 + c] * m;
        v5 += sa[5 * 64 + c] * m;
    }
    float ss = v0 * v0 + v1 * v1 + v2 * v2 + v3 * v3 + v4 * v4 + v5 * v5;
    float rms = sqrtf(ss * (1.0f / 9.0f) + 1e-7f);
    float sc = gam[t] / rms;
    float* op = out + (size_t)n * 576;
    op[0 * 64 + t] = 0.f;
    op[2 * 64 + t] = 0.f;
    op[6 * 64 + t] = 0.f;
    op[1 * 64 + t] = v0 * sc;
    op[3 * 64 + t] = v1 * sc;
    op[4 * 64 + t] = v2 * sc;
    op[5 * 64 + t] = v3 * sc;
    op[7 * 64 + t] = v4 * sc;
    op[8 * 64 + t] = v5 * sc;
}

// ---------------------------------------------------------------------------
// Legacy fallback path (small ws): OLD-layout xm, LDS-phased rad, atomic
// scatter + separate finalize.
// ---------------------------------------------------------------------------
__global__ __launch_bounds__(256) void k_xm_legacy(const float* __restrict__ nf,
                                                   const float* __restrict__ m1,
                                                   float* __restrict__ xm6, int N)
{
    const int tid = threadIdx.x;
    const int w = tid >> 6;
    const int t = tid & 63;
    const int n = blockIdx.x * 4 + w;
    __shared__ float sx[4][6 * 64];
    if (n < N) {
        const float* xp = nf + (size_t)n * (SPHN * CHN);
        sx[w][0 * 64 + t] = xp[1 * 64 + t];
        sx[w][1 * 64 + t] = xp[3 * 64 + t];
        sx[w][2 * 64 + t] = xp[4 * 64 + t];
        sx[w][3 * 64 + t] = xp[5 * 64 + t];
        sx[w][4 * 64 + t] = xp[7 * 64 + t];
        sx[w][5 * 64 + t] = xp[8 * 64 + t];
    }
    __syncthreads();
    if (n >= N) return;
    float a0 = 0.f, a1 = 0.f, a2 = 0.f, a3 = 0.f, a4 = 0.f, a5 = 0.f;
    for (int c = 0; c < 64; ++c) {
        float m = m1[c * 64 + t];
        a0 += sx[w][0 * 64 + c] * m;
        a1 += sx[w][1 * 64 + c] * m;
        a2 += sx[w][2 * 64 + c] * m;
        a3 += sx[w][3 * 64 + c] * m;
        a4 += sx[w][4 * 64 + c] * m;
        a5 += sx[w][5 * 64 + c] * m;
    }
    float* op = xm6 + (size_t)n * 384;
    op[0 * 64 + t] = a0;
    op[1 * 64 + t] = a1;
    op[2 * 64 + t] = a2;
    op[3 * 64 + t] = a3;
    op[4 * 64 + t] = a4;
    op[5 * 64 + t] = a5;
}

__global__ __launch_bounds__(256, 4) void k_rad_lds(const float* __restrict__ evec,
                                                    const float* __restrict__ w1,
                                                    const float* __restrict__ b1,
                                                    const float* __restrict__ w2,
                                                    float* __restrict__ radg,
                                                    int E)
{
    __shared__ float rbfT[64 * 64];
    __shared__ float hT[32 * 64];
    __shared__ float distS[64];
    __shared__ float envS[64];
    const int tid = threadIdx.x;
    const int base = blockIdx.x * 64;

    if (tid < 64) {
        int e = base + tid;
        float dist = 0.f;
        if (e < E) {
            float vx = evec[(size_t)e * 3 + 0];
            float vy = evec[(size_t)e * 3 + 1];
            float vz = evec[(size_t)e * 3 + 2];
            dist = sqrtf(vx * vx + vy * vy + vz * vz);
        }
        distS[tid] = dist;
        float dd = dist * (1.0f / 6.0f);
        float env = 0.f;
        if (dd < 1.0f) {
            float d2 = dd * dd;
            float d5 = d2 * d2 * dd;
            env = 1.0f - 21.0f * d5 + 35.0f * d5 * dd - 15.0f * d5 * d2;
        }
        envS[tid] = env;
    }
    __syncthreads();

    const float step = 6.0f / 63.0f;
#pragma unroll
    for (int p = 0; p < 16; ++p) {
        int idx = p * 256 + tid;
        int k = idx >> 6, e2 = idx & 63;
        float diff = distS[e2] - step * (float)k;
        rbfT[idx] = __expf(-55.125f * diff * diff);
    }

    const int egB = tid & 15;
    const int jgB = tid >> 4;
    const int egC = tid >> 4;
    const int tgC = tid & 15;

    float acc[4][4];
#pragma unroll
    for (int ee = 0; ee < 4; ++ee)
#pragma unroll
        for (int cc = 0; cc < 4; ++cc) acc[ee][cc] = 0.f;

    for (int q = 0; q < 4; ++q) {
        float h00, h01, h10, h11, h20, h21, h30, h31;
        {
            const float2 bb = *(const float2*)&b1[q * 32 + jgB * 2];
            h00 = bb.x; h01 = bb.y; h10 = bb.x; h11 = bb.y;
            h20 = bb.x; h21 = bb.y; h30 = bb.x; h31 = bb.y;
            const float* w1p = w1 + q * 32 + jgB * 2;
#pragma unroll 4
            for (int k = 0; k < 64; ++k) {
                float2 wv = *(const float2*)&w1p[k * 128];
                float4 rb = *(const float4*)&rbfT[k * 64 + egB * 4];
                h00 += rb.x * wv.x; h01 += rb.x * wv.y;
                h10 += rb.y * wv.x; h11 += rb.y * wv.y;
                h20 += rb.z * wv.x; h21 += rb.z * wv.y;
                h30 += rb.w * wv.x; h31 += rb.w * wv.y;
            }
        }
        __syncthreads();
        {
            float4 v0, v1;
            v0.x = siluf(h00); v0.y = siluf(h10); v0.z = siluf(h20); v0.w = siluf(h30);
            v1.x = siluf(h01); v1.y = siluf(h11); v1.z = siluf(h21); v1.w = siluf(h31);
            *(float4*)&hT[(jgB * 2 + 0) * 64 + egB * 4] = v0;
            *(float4*)&hT[(jgB * 2 + 1) * 64 + egB * 4] = v1;
        }
        __syncthreads();

        const float* w2p = w2 + (size_t)(q * 32) * 64 + tgC * 4;
#pragma unroll 4
        for (int j2 = 0; j2 < 32; ++j2) {
            float4 wv = *(const float4*)&w2p[j2 * 64];
            float4 hv = *(const float4*)&hT[j2 * 64 + egC * 4];
            acc[0][0] += hv.x * wv.x; acc[0][1] += hv.x * wv.y;
            acc[0][2] += hv.x * wv.z; acc[0][3] += hv.x * wv.w;
            acc[1][0] += hv.y * wv.x; acc[1][1] += hv.y * wv.y;
            acc[1][2] += hv.y * wv.z; acc[1][3] += hv.y * wv.w;
            acc[2][0] += hv.z * wv.x; acc[2][1] += hv.z * wv.y;
            acc[2][2] += hv.z * wv.z; acc[2][3] += hv.z * wv.w;
            acc[3][0] += hv.w * wv.x; acc[3][1] += hv.w * wv.y;
            acc[3][2] += hv.w * wv.z; acc[3][3] += hv.w * wv.w;
        }
    }

#pragma unroll
    for (int ee = 0; ee < 4; ++ee) {
        int e = base + egC * 4 + ee;
        if (e < E) {
            float envv = envS[egC * 4 + ee];
            float4 o;
            o.x = acc[ee][0] * envv;
            o.y = acc[ee][1] * envv;
            o.z = acc[ee][2] * envv;
            o.w = acc[ee][3] * envv;
            *(float4*)&radg[(size_t)e * 64 + tgC * 4] = o;
        }
    }
}

__device__ __forceinline__ float wig_entry(int l, int i, int j, float bA, float cA,
                                           const float* __restrict__ J, int n)
{
    if (i == l) return 0.f;
    const int j2 = 2 * l - j;
    float Pij = 0.f, Pij2 = 0.f;
    for (int k = 0; k < n; ++k) {
        float sbk, cbk;
        __sincosf((float)(l - k) * bA, &sbk, &cbk);
        if (k == l) cbk = 0.f;
        float zj  = cbk * J[k * n + j]  + sbk * J[(2 * l - k) * n + j];
        float zj2 = cbk * J[k * n + j2] + sbk * J[(2 * l - k) * n + j2];
        Pij  += J[i * n + k] * zj;
        Pij2 += J[i * n + k] * zj2;
    }
    float s_, c_;
    __sincosf((float)(l - j) * cA, &s_, &c_);
    float czj = (j == l) ? 0.f : c_;
    float szj = -s_;
    return Pij * czj + Pij2 * szj;
}

__global__ __launch_bounds__(64) void k_edge2(const float* __restrict__ evec,
                                              const int* __restrict__ eidx,
                                              const float* __restrict__ radg,
                                              const float* __restrict__ Jc,
                                              const float* __restrict__ xm6,
                                              float* __restrict__ acc, int E)
{
    const int e = blockIdx.x;
    const int t = threadIdx.x;
    __shared__ float s_W1[9], s_W2[25], s_Q1[9], s_Q2[25];

    float vx = evec[(size_t)e * 3 + 0];
    float vy = evec[(size_t)e * 3 + 1];
    float vz = evec[(size_t)e * 3 + 2];
    float dist = sqrtf(vx * vx + vy * vy + vz * vz);
    float inv = 1.0f / fmaxf(dist, 1e-7f);
    float xn = fminf(fmaxf(vx * inv, -1.f), 1.f);
    float yn = fminf(fmaxf(vy * inv, -1.f), 1.f);
    float zn = fminf(fmaxf(vz * inv, -1.f), 1.f);
    float beta = acosf(fminf(fmaxf(yn, -1.f + 1e-7f), 1.f - 1e-7f));
    float alpha = atan2f(xn, zn);
    float bA = -beta;
    float cA = -alpha;

    if (t < 25) {
        s_W2[t] = wig_entry(2, t / 5, t % 5, bA, cA, Jc + 9, 5);
    } else if (t >= 32 && t < 41) {
        int u = t - 32;
        s_W1[u] = wig_entry(1, u / 3, u % 3, bA, cA, Jc, 3);
    }
    __syncthreads();

    if (t < 25) {
        int i = t / 5, j = t % 5;
        float qv = 0.f;
#pragma unroll
        for (int k = 0; k < 5; ++k) qv += s_W2[k * 5 + i] * s_W2[k * 5 + j];
        s_Q2[t] = qv;
    } else if (t >= 32 && t < 41) {
        int u = t - 32;
        int i = u / 3, j = u % 3;
        float qv = 0.f;
#pragma unroll
        for (int k = 0; k < 3; ++k) qv += s_W1[k * 3 + i] * s_W1[k * 3 + j];
        s_Q1[u] = qv;
    }
    __syncthreads();

    const float rad = radg[(size_t)e * 64 + t];
    const int src = eidx[e];
    const int dst = eidx[E + e];
    const float* xs = xm6 + (size_t)src * 384;
    float x1 = xs[0 * 64 + t];
    float x3 = xs[1 * 64 + t];
    float x4 = xs[2 * 64 + t];
    float x5 = xs[3 * 64 + t];
    float x7 = xs[4 * 64 + t];
    float x8 = xs[5 * 64 + t];

    float m1v = rad * (s_Q1[0] * x1 + s_Q1[2] * x3);
    float m3v = rad * (s_Q1[6] * x1 + s_Q1[8] * x3);
    float m4v = rad * (s_Q2[0]  * x4 + s_Q2[1]  * x5 + s_Q2[3]  * x7 + s_Q2[4]  * x8);
    float m5v = rad * (s_Q2[5]  * x4 + s_Q2[6]  * x5 + s_Q2[8]  * x7 + s_Q2[9]  * x8);
    float m7v = rad * (s_Q2[15] * x4 + s_Q2[16] * x5 + s_Q2[18] * x7 + s_Q2[19] * x8);
    float m8v = rad * (s_Q2[20] * x4 + s_Q2[21] * x5 + s_Q2[23] * x7 + s_Q2[24] * x8);

    float* ad = acc + (size_t)dst * 576;
    atomicAdd(ad + 1 * 64 + t, m1v);
    atomicAdd(ad + 3 * 64 + t, m3v);
    atomicAdd(ad + 4 * 64 + t, m4v);
    atomicAdd(ad + 5 * 64 + t, m5v);
    atomicAdd(ad + 7 * 64 + t, m7v);
    atomicAdd(ad + 8 * 64 + t, m8v);
}

__global__ __launch_bounds__(64) void k_fin(const float* __restrict__ m2,
                                            const float* __restrict__ gam,
                                            float* __restrict__ out)
{
    const int n = blockIdx.x;
    const int t = threadIdx.x;
    __shared__ float sa[6 * 64];
    float* op = out + (size_t)n * 576;
    sa[0 * 64 + t] = op[1 * 64 + t];
    sa[1 * 64 + t] = op[3 * 64 + t];
    sa[2 * 64 + t] = op[4 * 64 + t];
    sa[3 * 64 + t] = op[5 * 64 + t];
    sa[4 * 64 + t] = op[7 * 64 + t];
    sa[5 * 64 + t] = op[8 * 64 + t];
    __syncthreads();
    float v0 = 0.f, v1 = 0.f, v2 = 0.f, v3 = 0.f, v4 = 0.f, v5 = 0.f;
    for (int c = 0; c < 64; ++c) {
        float m = m2[c * 64 + t];
        v0 += sa[0 * 64 + c] * m;
        v1 += sa[1 * 64 + c] * m;
        v2 += sa[2 * 64 + c] * m;
        v3 += sa[3 * 64 + c] * m;
        v4 += sa[4 * 64 + c] * m;
        v5 += sa[5 * 64 + c] * m;
    }
    float ss = v0 * v0 + v1 * v1 + v2 * v2 + v3 * v3 + v4 * v4 + v5 * v5;
    float rms = sqrtf(ss * (1.0f / 9.0f) + 1e-7f);
    float sc = gam[t] / rms;
    op[0 * 64 + t] = 0.f;
    op[2 * 64 + t] = 0.f;
    op[6 * 64 + t] = 0.f;
    op[1 * 64 + t] = v0 * sc;
    op[3 * 64 + t] = v1 * sc;
    op[4 * 64 + t] = v2 * sc;
    op[5 * 64 + t] = v3 * sc;
    op[7 * 64 + t] = v4 * sc;
    op[8 * 64 + t] = v5 * sc;
}

static inline size_t align256(size_t x) { return (x + 255) & ~(size_t)255; }

extern "C" void kernel_launch(void* const* d_in, const int* in_sizes, int n_in,
                              void* d_out, int out_size, void* d_ws, size_t ws_size,
                              hipStream_t stream)
{
    const float* nf  = (const float*)d_in[0];
    const float* ev  = (const float*)d_in[1];
    const int*   ei  = (const int*)d_in[2];
    const float* w1  = (const float*)d_in[3];
    const float* b1  = (const float*)d_in[4];
    const float* w2  = (const float*)d_in[5];
    const float* m1  = (const float*)d_in[6];
    const float* m2  = (const float*)d_in[7];
    const float* gam = (const float*)d_in[8];

    const int N = in_sizes[0] / (SPHN * CHN);
    const int E = in_sizes[1] / 3;

    float* out = (float*)d_out;
    char* base = (char*)d_ws;

    // ---- New-path layout ----
    size_t off = 0;
    float* Jc = (float*)(base + off);      off += align256(34 * sizeof(float));
    float* xm6n = (float*)(base + off);    off += align256((size_t)N * 512 * sizeof(float));
    float* table = (float*)(base + off);   off += align256((size_t)TABLE_N * 64 * sizeof(float));
    float* Qe24 = (float*)(base + off);    off += align256((size_t)E * 24 * sizeof(float));
    int* counts = (int*)(base + off);      off += align256((size_t)N * sizeof(int));
    int* offsets = (int*)(base + off);     off += align256((size_t)(N + 1) * sizeof(int));
    int* cursors = (int*)(base + off);     off += align256((size_t)N * sizeof(int));
    int* srcs = (int*)(base + off);        off += align256((size_t)E * sizeof(int));
    size_t need_new = off;

    // ---- Fallback layout (shares Jc at 0) ----
    size_t offF = align256(34 * sizeof(float));
    float* xm6o = (float*)(base + offF);   offF += align256((size_t)N * 384 * sizeof(float));
    float* radg = (float*)(base + offF);   offF += align256((size_t)E * 64 * sizeof(float));
    size_t need_old = offF;

    if (ws_size >= need_new) {
        hipLaunchKernelGGL(k_setup, dim3((N + 255) / 256), dim3(256), 0, stream,
                           Jc, counts, N);
        hipLaunchKernelGGL(k_hist, dim3((E + 255) / 256), dim3(256), 0, stream,
                           ei, counts, E);
        hipLaunchKernelGGL(k_scan, dim3(1), dim3(1024), 0, stream,
                           counts, offsets, cursors, N);
        hipLaunchKernelGGL(k_xm, dim3((N + 3) / 4), dim3(256), 0, stream,
                           nf, m1, xm6n, N);
        hipLaunchKernelGGL(k_radtab, dim3((TABLE_N + 63) / 64), dim3(256), 0, stream,
                           w1, b1, w2, table);
        hipLaunchKernelGGL(k_edgeQS, dim3((E + 255) / 256), dim3(256), 0, stream,
                           ev, ei, Jc, cursors, Qe24, srcs, E);
        hipLaunchKernelGGL(k_gather_fin, dim3(N), dim3(64), 0, stream,
                           srcs, offsets, Qe24, table, xm6n, m2, gam, out);
    } else if (ws_size >= need_old) {
        hipLaunchKernelGGL(k_setup, dim3(1), dim3(256), 0, stream,
                           Jc, (int*)nullptr, 0);
        hipLaunchKernelGGL(k_xm_legacy, dim3((N + 3) / 4), dim3(256), 0, stream,
                           nf, m1, xm6o, N);
        hipMemsetAsync(d_out, 0, (size_t)out_size * sizeof(float), stream);
        hipLaunchKernelGGL(k_rad_lds, dim3((E + 63) / 64), dim3(256), 0, stream,
                           ev, w1, b1, w2, radg, E);
        hipLaunchKernelGGL(k_edge2, dim3(E), dim3(64), 0, stream,
                           ev, ei, radg, Jc, xm6o, out, E);
        hipLaunchKernelGGL(k_fin, dim3(N), dim3(64), 0, stream, m2, gam, out);
    }
}